// Round 2
// baseline (524.612 us; speedup 1.0000x reference)
//
#include <hip/hip_runtime.h>

typedef __bf16 bf16_t;
typedef bf16_t bf16x8 __attribute__((ext_vector_type(8)));
typedef float f32x4 __attribute__((ext_vector_type(4)));
typedef unsigned short u16;
typedef u16 u16x8 __attribute__((ext_vector_type(8)));
typedef unsigned int u32;
typedef u32 u32x4 __attribute__((ext_vector_type(4)));

#define E_TOT 524288
#define MT 128
#define NBLK (E_TOT / MT)

// round-to-nearest-even f32 -> bf16
__device__ __forceinline__ u16 f2bf(float f) {
  u32 u = __builtin_bit_cast(u32, f);
  u += 0x7FFFu + ((u >> 16) & 1u);
  return (u16)(u >> 16);
}

__device__ __forceinline__ u16x8 pack8(f32x4 a, f32x4 b) {
  u16x8 p;
  p[0] = f2bf(a[0]); p[1] = f2bf(a[1]); p[2] = f2bf(a[2]); p[3] = f2bf(a[3]);
  p[4] = f2bf(b[0]); p[5] = f2bf(b[1]); p[6] = f2bf(b[2]); p[7] = f2bf(b[3]);
  return p;
}

// W1 [384][256] f32 -> W1T [256][384] bf16
__global__ void prep_w1t(const float* __restrict__ W1, u16* __restrict__ W1T) {
  int t = blockIdx.x * 256 + threadIdx.x;
  if (t < 256 * 384) {
    int n = t / 384, k = t % 384;
    W1T[t] = f2bf(W1[k * 256 + n]);
  }
}
// W2 [256][64] f32 -> W2T [64][256] bf16
__global__ void prep_w2t(const float* __restrict__ W2, u16* __restrict__ W2T) {
  int t = blockIdx.x * 256 + threadIdx.x;
  if (t < 64 * 256) {
    int n = t / 256, k = t % 256;
    W2T[t] = f2bf(W2[k * 64 + n]);
  }
}

// Fused: x = [src|dest|edge|u[batch]] (E x 384); h = relu(x@W1+b1); out = h@W2+b2
__global__ void __launch_bounds__(512, 4) edge_fused(
    const float* __restrict__ src, const float* __restrict__ dst,
    const float* __restrict__ ea, const float* __restrict__ u,
    const int* __restrict__ batch, const u16* __restrict__ W1T,
    const float* __restrict__ b1, const u16* __restrict__ W2T,
    const float* __restrict__ b2, float* __restrict__ out)
{
  // 65536 B LDS, phase-overlaid:
  //  phase1: As[128][72] @ 0 (9216 u16), Ws[256][72] @ 9216 (18432 u16)
  //  phase2: Hs[64][256] swz @ 0 (16384 u16), W2s[64][256] swz @ 16384 (16384 u16)
  __shared__ __align__(16) u16 smem[32768];
  u16* As  = smem;
  u16* Ws  = smem + 9216;
  u16* Hs  = smem;
  u16* W2s = smem + 16384;

  const int t    = threadIdx.x;
  const int wid  = t >> 6;
  const int lane = t & 63;
  const int lr   = lane & 15;
  const int lg   = lane >> 4;
  const int wr   = wid >> 2;   // 0..1 : row half of M-tile
  const int wc   = wid & 3;    // 0..3 : 64-col slice of HIDDEN
  const int e0   = blockIdx.x * MT;

  f32x4 acc[4][4];
  #pragma unroll
  for (int i = 0; i < 4; ++i)
    #pragma unroll
    for (int j = 0; j < 4; ++j)
      acc[i][j] = (f32x4){0.f, 0.f, 0.f, 0.f};

  const int r  = t >> 2;          // staging row 0..127
  const int cg = (t & 3) << 4;    // staging col base {0,16,32,48}

  // prefetch registers for next chunk
  f32x4 pa[4];
  u32x4 pw[4];

  auto issue = [&](int kb) {
    const float* rowp;
    if (kb < 2)       rowp = src + (size_t)(e0 + r) * 128 + kb * 64;
    else if (kb < 4)  rowp = dst + (size_t)(e0 + r) * 128 + (kb - 2) * 64;
    else if (kb == 4) rowp = ea + (size_t)(e0 + r) * 64;
    else              rowp = u + (size_t)batch[e0 + r] * 64;
    pa[0] = *(const f32x4*)(rowp + cg + 0);
    pa[1] = *(const f32x4*)(rowp + cg + 4);
    pa[2] = *(const f32x4*)(rowp + cg + 8);
    pa[3] = *(const f32x4*)(rowp + cg + 12);
    #pragma unroll
    for (int it = 0; it < 4; ++it) {
      int idx = t + it * 512;
      int n = idx >> 3, j = idx & 7;
      pw[it] = *(const u32x4*)(W1T + n * 384 + kb * 64 + j * 8);
    }
  };

  issue(0);

  #pragma unroll
  for (int kb = 0; kb < 6; ++kb) {
    __syncthreads();  // previous MFMA phase done reading LDS
    // ---- write prefetched chunk kb to LDS ----
    *(u16x8*)&As[r * 72 + cg + 0] = pack8(pa[0], pa[1]);
    *(u16x8*)&As[r * 72 + cg + 8] = pack8(pa[2], pa[3]);
    #pragma unroll
    for (int it = 0; it < 4; ++it) {
      int idx = t + it * 512;
      int n = idx >> 3, j = idx & 7;
      *(u32x4*)&Ws[n * 72 + j * 8] = pw[it];
    }
    // ---- issue next chunk's global loads (hide under barrier+MFMA) ----
    if (kb < 5) issue(kb + 1);
    __syncthreads();

    // ---- MFMA: 2 k-steps of 32 ----
    #pragma unroll
    for (int ks = 0; ks < 2; ++ks) {
      bf16x8 af[4];
      #pragma unroll
      for (int mf = 0; mf < 4; ++mf)
        af[mf] = *(const bf16x8*)&As[(wr * 64 + mf * 16 + lr) * 72 + ks * 32 + lg * 8];
      #pragma unroll
      for (int nf = 0; nf < 4; ++nf) {
        bf16x8 bfr = *(const bf16x8*)&Ws[(wc * 64 + nf * 16 + lr) * 72 + ks * 32 + lg * 8];
        #pragma unroll
        for (int mf = 0; mf < 4; ++mf)
          acc[mf][nf] = __builtin_amdgcn_mfma_f32_16x16x32_bf16(af[mf], bfr, acc[mf][nf], 0, 0, 0);
      }
    }
  }
  __syncthreads();  // all As/Ws reads done before overlay

  // ---- stage W2s (XOR-swizzled [64][256]) ----
  #pragma unroll
  for (int it = 0; it < 4; ++it) {
    int idx = t + it * 512;
    int n = idx >> 5, j = idx & 31;
    u32x4 d = *(const u32x4*)(W2T + n * 256 + j * 8);
    *(u32x4*)&W2s[n * 256 + ((j ^ (n & 7)) << 3)] = d;
  }

  float bias1[4];
  #pragma unroll
  for (int nf = 0; nf < 4; ++nf) bias1[nf] = b1[wc * 64 + nf * 16 + lr];

  // layer 2 wave assignment: 16 fragments of the 64x64 half-tile, 2 per wave
  const int mf2 = wid >> 1;             // a-frag row block (shared by both frags)
  const int nf2a = (wid & 1) * 2;       // b-frag col blocks
  const int nf2b = nf2a + 1;
  const float bb_a = b2[nf2a * 16 + lr];
  const float bb_b = b2[nf2b * 16 + lr];

  #pragma unroll
  for (int half = 0; half < 2; ++half) {
    // ---- waves owning this row-half write h = relu(acc+b1) -> Hs swizzled ----
    if (wr == half) {
      #pragma unroll
      for (int mf = 0; mf < 4; ++mf)
        #pragma unroll
        for (int nf = 0; nf < 4; ++nf)
          #pragma unroll
          for (int rr = 0; rr < 4; ++rr) {
            int row = mf * 16 + lg * 4 + rr;          // 0..63 within half
            int col = wc * 64 + nf * 16 + lr;
            float v = fmaxf(acc[mf][nf][rr] + bias1[nf], 0.f);
            Hs[row * 256 + ((((col >> 3) ^ (row & 7)) << 3) | (col & 7))] = f2bf(v);
          }
    }
    __syncthreads();

    // ---- layer 2 for this half: all 8 waves, 2 frags each ----
    f32x4 acc2a = (f32x4){0.f, 0.f, 0.f, 0.f};
    f32x4 acc2b = (f32x4){0.f, 0.f, 0.f, 0.f};
    const int rowA = mf2 * 16 + lr;
    #pragma unroll
    for (int ks = 0; ks < 8; ++ks) {
      bf16x8 a = *(const bf16x8*)&Hs[rowA * 256 + (((ks * 4 + lg) ^ (rowA & 7)) << 3)];
      int nA = nf2a * 16 + lr;
      int nB = nf2b * 16 + lr;
      bf16x8 ba = *(const bf16x8*)&W2s[nA * 256 + (((ks * 4 + lg) ^ (nA & 7)) << 3)];
      bf16x8 bb = *(const bf16x8*)&W2s[nB * 256 + (((ks * 4 + lg) ^ (nB & 7)) << 3)];
      acc2a = __builtin_amdgcn_mfma_f32_16x16x32_bf16(a, ba, acc2a, 0, 0, 0);
      acc2b = __builtin_amdgcn_mfma_f32_16x16x32_bf16(a, bb, acc2b, 0, 0, 0);
    }

    // ---- epilogue: out = acc2 + b2 (f32) ----
    #pragma unroll
    for (int rr = 0; rr < 4; ++rr) {
      int row = e0 + half * 64 + mf2 * 16 + lg * 4 + rr;
      out[row * 64 + nf2a * 16 + lr] = acc2a[rr] + bb_a;
      out[row * 64 + nf2b * 16 + lr] = acc2b[rr] + bb_b;
    }
    __syncthreads();  // Hs reads done before next half overwrites
  }
}

extern "C" void kernel_launch(void* const* d_in, const int* in_sizes, int n_in,
                              void* d_out, int out_size, void* d_ws, size_t ws_size,
                              hipStream_t stream) {
  const float* src  = (const float*)d_in[0];
  const float* dst  = (const float*)d_in[1];
  const float* ea   = (const float*)d_in[2];
  const float* u    = (const float*)d_in[3];
  const int* batch  = (const int*)d_in[4];
  const float* W1   = (const float*)d_in[5];
  const float* b1   = (const float*)d_in[6];
  const float* W2   = (const float*)d_in[7];
  const float* b2   = (const float*)d_in[8];
  float* out = (float*)d_out;

  u16* W1T = (u16*)d_ws;            // 256*384 bf16
  u16* W2T = W1T + 256 * 384;       // 64*256 bf16

  prep_w1t<<<(256 * 384 + 255) / 256, 256, 0, stream>>>(W1, W1T);
  prep_w2t<<<(64 * 256 + 255) / 256, 256, 0, stream>>>(W2, W2T);
  edge_fused<<<NBLK, 512, 0, stream>>>(src, dst, ea, u, batch, W1T, b1, W2T, b2, out);
}

// Round 3
// 313.791 us; speedup vs baseline: 1.6719x; 1.6719x over previous
//
#include <hip/hip_runtime.h>

typedef __bf16 bf16_t;
typedef bf16_t bf16x8 __attribute__((ext_vector_type(8)));
typedef float f32x4 __attribute__((ext_vector_type(4)));
typedef unsigned short u16;
typedef u16 u16x8 __attribute__((ext_vector_type(8)));
typedef unsigned int u32;
typedef u32 u32x4 __attribute__((ext_vector_type(4)));

#define E_TOT 524288
#define MT 64
#define NBLK (E_TOT / MT)

// round-to-nearest-even f32 -> bf16
__device__ __forceinline__ u16 f2bf(float f) {
  u32 u = __builtin_bit_cast(u32, f);
  u += 0x7FFFu + ((u >> 16) & 1u);
  return (u16)(u >> 16);
}

__device__ __forceinline__ u16x8 pack8(f32x4 a, f32x4 b) {
  u16x8 p;
  p[0] = f2bf(a[0]); p[1] = f2bf(a[1]); p[2] = f2bf(a[2]); p[3] = f2bf(a[3]);
  p[4] = f2bf(b[0]); p[5] = f2bf(b[1]); p[6] = f2bf(b[2]); p[7] = f2bf(b[3]);
  return p;
}

__device__ __forceinline__ void gload_lds16(const void* g, void* l) {
  __builtin_amdgcn_global_load_lds(
      (const __attribute__((address_space(1))) u32*)g,
      (__attribute__((address_space(3))) u32*)l, 16, 0, 0);
}

// W1 [384][256] f32 -> W1Ts bf16, chunked + inverse-swizzled for linear
// global_load_lds. 16-B unit U = kb*2048 + n*8 + jswz holds
// W1^T[n][kb*64 + ((jswz^(n&7))*8) .. +8)   (so a swizzled ds_read is correct)
__global__ void prep_w1ts(const float* __restrict__ W1, u16* __restrict__ W1Ts) {
  int t = blockIdx.x * 256 + threadIdx.x;  // 0..98303
  if (t < 384 * 256) {
    int U = t >> 3, e = t & 7;
    int kb = U >> 11, rem = U & 2047;
    int n = rem >> 3, jswz = rem & 7;
    int k = kb * 64 + ((jswz ^ (n & 7)) << 3) + e;
    W1Ts[t] = f2bf(W1[k * 256 + n]);
  }
}

// W2 [256][64] f32 -> W2T [64][256] bf16 (row-major, read direct from global)
__global__ void prep_w2t(const float* __restrict__ W2, u16* __restrict__ W2T) {
  int t = blockIdx.x * 256 + threadIdx.x;
  if (t < 64 * 256) {
    int n = t / 256, k = t % 256;
    W2T[t] = f2bf(W2[k * 64 + n]);
  }
}

// Fused: x = [src|dest|edge|u[batch]] (E x 384); h = relu(x@W1+b1); out = h@W2+b2
__global__ void __launch_bounds__(256) edge_fused(
    const float* __restrict__ src, const float* __restrict__ dst,
    const float* __restrict__ ea, const float* __restrict__ u,
    const int* __restrict__ batch, const u16* __restrict__ W1Ts,
    const float* __restrict__ b1, const u16* __restrict__ W2T,
    const float* __restrict__ b2, float* __restrict__ out)
{
  // 40960 B LDS:
  //  phase1: As[64][64] swz @ 0 (4096 u16), Ws[256][64] swz @ 4096 (16384 u16)
  //  phase2: Hs[64][256] swz @ 0 (16384 u16)
  __shared__ __align__(16) u16 smem[20480];
  u16* As = smem;
  u16* Ws = smem + 4096;
  u16* Hs = smem;

  const int t    = threadIdx.x;
  const int wid  = t >> 6;
  const int lane = t & 63;
  const int lr   = lane & 15;
  const int lg   = lane >> 4;
  const int e0   = blockIdx.x * MT;

  f32x4 acc[4][4];
  #pragma unroll
  for (int i = 0; i < 4; ++i)
    #pragma unroll
    for (int j = 0; j < 4; ++j)
      acc[i][j] = (f32x4){0.f, 0.f, 0.f, 0.f};

  const int r  = t >> 2;          // staging row 0..63
  const int cg = (t & 3) << 4;    // staging col base {0,16,32,48}

  f32x4 pa[4];                    // A prefetch (the HBM-latency path)
  auto issueA = [&](int kb) {
    const float* rowp;
    if (kb < 2)       rowp = src + (size_t)(e0 + r) * 128 + kb * 64;
    else if (kb < 4)  rowp = dst + (size_t)(e0 + r) * 128 + (kb - 2) * 64;
    else if (kb == 4) rowp = ea + (size_t)(e0 + r) * 64;
    else              rowp = u + (size_t)batch[e0 + r] * 64;
    pa[0] = *(const f32x4*)(rowp + cg + 0);
    pa[1] = *(const f32x4*)(rowp + cg + 4);
    pa[2] = *(const f32x4*)(rowp + cg + 8);
    pa[3] = *(const f32x4*)(rowp + cg + 12);
  };

  issueA(0);

  #pragma unroll
  for (int kb = 0; kb < 6; ++kb) {
    __syncthreads();  // previous chunk's LDS reads done

    // ---- write A chunk (swizzled): row r, 16-B units j0,j1 ----
    {
      u16x8 lo = pack8(pa[0], pa[1]);
      u16x8 hi = pack8(pa[2], pa[3]);
      int j0 = (t & 3) * 2;
      *(u16x8*)&As[r * 64 + ((j0 ^ (r & 7)) << 3)]       = lo;
      *(u16x8*)&As[r * 64 + (((j0 + 1) ^ (r & 7)) << 3)] = hi;
    }

    // ---- async-stage Ws: 8 global_load_lds x 1KB per wave ----
    #pragma unroll
    for (int it = 0; it < 8; ++it) {
      int ubase = (it * 4 + wid) * 64;                  // wave-uniform
      gload_lds16(W1Ts + ((size_t)kb * 2048 + ubase + lane) * 8,
                  &Ws[ubase * 8]);
    }
    asm volatile("s_waitcnt vmcnt(0)" ::: "memory");    // only glds in flight here
    __syncthreads();

    if (kb < 5) issueA(kb + 1);  // fly during MFMA phase

    // ---- MFMA: 2 k-steps of 32 ----
    #pragma unroll
    for (int ks = 0; ks < 2; ++ks) {
      bf16x8 af[4];
      #pragma unroll
      for (int mf = 0; mf < 4; ++mf) {
        int row = mf * 16 + lr;
        af[mf] = *(const bf16x8*)&As[row * 64 + (((ks * 4 + lg) ^ (row & 7)) << 3)];
      }
      #pragma unroll
      for (int nf = 0; nf < 4; ++nf) {
        int n = wid * 64 + nf * 16 + lr;
        bf16x8 bfr = *(const bf16x8*)&Ws[n * 64 + (((ks * 4 + lg) ^ (n & 7)) << 3)];
        #pragma unroll
        for (int mf = 0; mf < 4; ++mf)
          acc[mf][nf] = __builtin_amdgcn_mfma_f32_16x16x32_bf16(af[mf], bfr, acc[mf][nf], 0, 0, 0);
      }
    }
  }
  __syncthreads();  // all As/Ws reads done before Hs overlay

  // ---- h = relu(acc + b1) -> Hs (XOR-swizzled [64][256]) ----
  float bias1[4];
  #pragma unroll
  for (int nf = 0; nf < 4; ++nf) bias1[nf] = b1[wid * 64 + nf * 16 + lr];
  #pragma unroll
  for (int mf = 0; mf < 4; ++mf)
    #pragma unroll
    for (int nf = 0; nf < 4; ++nf)
      #pragma unroll
      for (int rr = 0; rr < 4; ++rr) {
        int row = mf * 16 + lg * 4 + rr;
        int col = wid * 64 + nf * 16 + lr;
        float v = fmaxf(acc[mf][nf][rr] + bias1[nf], 0.f);
        Hs[row * 256 + ((((col >> 3) ^ (row & 7)) << 3) | (col & 7))] = f2bf(v);
      }
  __syncthreads();

  // ---- layer 2: out_tile[64][64] = Hs @ W2, B-frags direct from global ----
  f32x4 acc2[4];
  #pragma unroll
  for (int nf = 0; nf < 4; ++nf) acc2[nf] = (f32x4){0.f, 0.f, 0.f, 0.f};
  const int rowA = wid * 16 + lr;
  #pragma unroll
  for (int ks = 0; ks < 8; ++ks) {
    bf16x8 a = *(const bf16x8*)&Hs[rowA * 256 + (((ks * 4 + lg) ^ (rowA & 7)) << 3)];
    #pragma unroll
    for (int nf = 0; nf < 4; ++nf) {
      int n = nf * 16 + lr;
      bf16x8 b = *(const bf16x8*)(W2T + n * 256 + ks * 32 + lg * 8);
      acc2[nf] = __builtin_amdgcn_mfma_f32_16x16x32_bf16(a, b, acc2[nf], 0, 0, 0);
    }
  }

  // ---- epilogue: out = acc2 + b2 (f32) ----
  #pragma unroll
  for (int nf = 0; nf < 4; ++nf) {
    float bb = b2[nf * 16 + lr];
    #pragma unroll
    for (int rr = 0; rr < 4; ++rr) {
      int row = e0 + wid * 16 + lg * 4 + rr;
      out[(size_t)row * 64 + nf * 16 + lr] = acc2[nf][rr] + bb;
    }
  }
}

extern "C" void kernel_launch(void* const* d_in, const int* in_sizes, int n_in,
                              void* d_out, int out_size, void* d_ws, size_t ws_size,
                              hipStream_t stream) {
  const float* src  = (const float*)d_in[0];
  const float* dst  = (const float*)d_in[1];
  const float* ea   = (const float*)d_in[2];
  const float* u    = (const float*)d_in[3];
  const int* batch  = (const int*)d_in[4];
  const float* W1   = (const float*)d_in[5];
  const float* b1   = (const float*)d_in[6];
  const float* W2   = (const float*)d_in[7];
  const float* b2   = (const float*)d_in[8];
  float* out = (float*)d_out;

  u16* W1Ts = (u16*)d_ws;            // 384*256 bf16 (chunked+swizzled)
  u16* W2T  = W1Ts + 384 * 256;      // 64*256 bf16

  prep_w1ts<<<(384 * 256 + 255) / 256, 256, 0, stream>>>(W1, W1Ts);
  prep_w2t<<<(64 * 256 + 255) / 256, 256, 0, stream>>>(W2, W2T);
  edge_fused<<<NBLK, 256, 0, stream>>>(src, dst, ea, u, batch, W1Ts, b1, W2T, b2, out);
}

// Round 4
// 236.948 us; speedup vs baseline: 2.2140x; 1.3243x over previous
//
#include <hip/hip_runtime.h>

typedef __bf16 bf16_t;
typedef bf16_t bf16x8 __attribute__((ext_vector_type(8)));
typedef float f32x4 __attribute__((ext_vector_type(4)));
typedef unsigned short u16;
typedef unsigned int u32;

#define E_TOT 524288
#define MT 64
#define NBLK (E_TOT / MT)

// round-to-nearest-even f32 -> bf16 (prep kernels)
__device__ __forceinline__ u16 f2bf(float f) {
  u32 u = __builtin_bit_cast(u32, f);
  u += 0x7FFFu + ((u >> 16) & 1u);
  return (u16)(u >> 16);
}

__device__ __forceinline__ bf16x8 pack8(f32x4 a, f32x4 b) {
  bf16x8 p;
  p[0] = (bf16_t)a[0]; p[1] = (bf16_t)a[1]; p[2] = (bf16_t)a[2]; p[3] = (bf16_t)a[3];
  p[4] = (bf16_t)b[0]; p[5] = (bf16_t)b[1]; p[6] = (bf16_t)b[2]; p[7] = (bf16_t)b[3];
  return p;
}

__device__ __forceinline__ void gload_lds16(const void* g, void* l) {
  __builtin_amdgcn_global_load_lds(
      (const __attribute__((address_space(1))) u32*)g,
      (__attribute__((address_space(3))) u32*)l, 16, 0, 0);
}

// W1 [384][256] f32 -> chunked+inverse-swizzled bf16 for linear global_load_lds.
// 16-B unit U = kb*2048 + n*8 + jswz holds W1^T[n][kb*64 + ((jswz^(n&7))*8) .. +8)
__global__ void prep_w1ts(const float* __restrict__ W1, u16* __restrict__ W1Ts) {
  int t = blockIdx.x * 256 + threadIdx.x;  // 0..98303
  if (t < 384 * 256) {
    int U = t >> 3, e = t & 7;
    int kb = U >> 11, rem = U & 2047;
    int n = rem >> 3, jswz = rem & 7;
    int k = kb * 64 + ((jswz ^ (n & 7)) << 3) + e;
    W1Ts[t] = f2bf(W1[k * 256 + n]);
  }
}

// W2 [256][64] f32 -> inverse-swizzled W2^T bf16 ("chunk 6", 32 KB).
// 16-B unit U = n*32 + uj holds W2^T[n][((uj^(n&7))*8) .. +8)
__global__ void prep_w2ts(const float* __restrict__ W2, u16* __restrict__ W2Ts) {
  int t = blockIdx.x * 256 + threadIdx.x;  // 0..16383
  if (t < 64 * 256) {
    int U = t >> 3, e = t & 7;
    int n = U >> 5, uj = U & 31;
    int k = ((uj ^ (n & 7)) << 3) + e;
    W2Ts[t] = f2bf(W2[k * 64 + n]);
  }
}

// Fused: x = [src|dest|edge|u[batch]] (E x 384); h = relu(x@W1+b1); out = h@W2+b2
__global__ void __launch_bounds__(256, 2) edge_fused(
    const float* __restrict__ src, const float* __restrict__ dst,
    const float* __restrict__ ea, const float* __restrict__ u,
    const int* __restrict__ batch, const u16* __restrict__ Wall,
    const float* __restrict__ b1, const float* __restrict__ b2,
    float* __restrict__ out)
{
  // 73728 B LDS: As[64][64]swz @0 (4096 u16), Wbuf0 @4096 (16384), Wbuf1 @20480 (16384)
  // overlays: W2s = Wbuf0 (staged as chunk 6), Hs = Wbuf1 (after last MFMA)
  __shared__ __align__(16) u16 smem[36864];
  u16* As  = smem;
  u16* Wb0 = smem + 4096;
  u16* Wb1 = smem + 20480;
  u16* W2s = Wb0;
  u16* Hs  = Wb1;

  const int t    = threadIdx.x;
  const int wid  = t >> 6;
  const int lane = t & 63;
  const int lr   = lane & 15;
  const int lg   = lane >> 4;
  const int e0   = blockIdx.x * MT;
  const int r    = t >> 2;          // A row owned by this thread
  const int cg   = (t & 3) << 4;    // A col base {0,16,32,48}
  const int j0   = (t & 3) * 2;     // As 16B-unit base

  // ---- A burst: all 6 chunks' 16 floats per thread, issued back-to-back ----
  f32x4 av[6][4];
  #pragma unroll
  for (int c = 0; c < 6; ++c) {
    const float* rowp;
    if (c < 2)       rowp = src + (size_t)(e0 + r) * 128 + c * 64;
    else if (c < 4)  rowp = dst + (size_t)(e0 + r) * 128 + (c - 2) * 64;
    else if (c == 4) rowp = ea + (size_t)(e0 + r) * 64;
    else             rowp = u + (size_t)batch[e0 + r] * 64;
    av[c][0] = *(const f32x4*)(rowp + cg + 0);
    av[c][1] = *(const f32x4*)(rowp + cg + 4);
    av[c][2] = *(const f32x4*)(rowp + cg + 8);
    av[c][3] = *(const f32x4*)(rowp + cg + 12);
  }

  // ---- stage W chunk 0 into Wb0 (after A burst, so A-consume waits keep it in flight) ----
  #pragma unroll
  for (int it = 0; it < 8; ++it) {
    int ubase = (it * 4 + wid) * 64;
    gload_lds16(Wall + ((size_t)ubase + lane) * 8, &Wb0[ubase * 8]);
  }

  // ---- convert A to bf16 registers (48 VGPRs), free the f32 burst regs ----
  bf16x8 ar[6][2];
  #pragma unroll
  for (int c = 0; c < 6; ++c) {
    ar[c][0] = pack8(av[c][0], av[c][1]);
    ar[c][1] = pack8(av[c][2], av[c][3]);
  }

  f32x4 acc[4][4];
  #pragma unroll
  for (int i = 0; i < 4; ++i)
    #pragma unroll
    for (int j = 0; j < 4; ++j)
      acc[i][j] = (f32x4){0.f, 0.f, 0.f, 0.f};

  // ---- K loop: 6 chunks of 64, W double-buffered, counted vmcnt ----
  #pragma unroll
  for (int kb = 0; kb < 6; ++kb) {
    u16* Wc = (kb & 1) ? Wb1 : Wb0;   // compute buffer (chunk kb)
    u16* Wn = (kb & 1) ? Wb0 : Wb1;   // stage buffer (chunk kb+1; kb=5 stages W2s)

    // write this chunk's A slice (swizzled) from registers
    *(bf16x8*)&As[r * 64 + ((j0 ^ (r & 7)) << 3)]       = ar[kb][0];
    *(bf16x8*)&As[r * 64 + (((j0 + 1) ^ (r & 7)) << 3)] = ar[kb][1];

    // stage chunk kb+1 (8 x 1KB glds per wave); chunk 6 == W2Ts
    #pragma unroll
    for (int it = 0; it < 8; ++it) {
      int ubase = (it * 4 + wid) * 64;
      gload_lds16(Wall + ((size_t)(kb + 1) * 2048 + ubase + lane) * 8, &Wn[ubase * 8]);
    }

    // chunk kb's 8 glds done (8 newest = chunk kb+1 stay in flight); As writes done
    asm volatile("s_waitcnt vmcnt(8)\n\ts_waitcnt lgkmcnt(0)" ::: "memory");
    __builtin_amdgcn_sched_barrier(0);
    __builtin_amdgcn_s_barrier();

    __builtin_amdgcn_s_setprio(1);
    #pragma unroll
    for (int ks = 0; ks < 2; ++ks) {
      bf16x8 af[4];
      #pragma unroll
      for (int mf = 0; mf < 4; ++mf) {
        int row = mf * 16 + lr;
        af[mf] = *(const bf16x8*)&As[row * 64 + (((ks * 4 + lg) ^ (row & 7)) << 3)];
      }
      #pragma unroll
      for (int nf = 0; nf < 4; ++nf) {
        int n = wid * 64 + nf * 16 + lr;
        bf16x8 bfr = *(const bf16x8*)&Wc[n * 64 + (((ks * 4 + lg) ^ (n & 7)) << 3)];
        #pragma unroll
        for (int mf = 0; mf < 4; ++mf)
          acc[mf][nf] = __builtin_amdgcn_mfma_f32_16x16x32_bf16(af[mf], bfr, acc[mf][nf], 0, 0, 0);
      }
    }
    __builtin_amdgcn_s_setprio(0);
    __builtin_amdgcn_s_barrier();   // chunk kb reads done before next stage overwrites Wc
  }

  // W2s (chunk 6) landed
  asm volatile("s_waitcnt vmcnt(0)" ::: "memory");

  // ---- h = relu(acc + b1) -> Hs (XOR-swizzled [64][256], overlays Wb1) ----
  float bias1[4];
  #pragma unroll
  for (int nf = 0; nf < 4; ++nf) bias1[nf] = b1[wid * 64 + nf * 16 + lr];
  #pragma unroll
  for (int mf = 0; mf < 4; ++mf)
    #pragma unroll
    for (int nf = 0; nf < 4; ++nf)
      #pragma unroll
      for (int rr = 0; rr < 4; ++rr) {
        int row = mf * 16 + lg * 4 + rr;
        int col = wid * 64 + nf * 16 + lr;
        float v = fmaxf(acc[mf][nf][rr] + bias1[nf], 0.f);
        *(bf16_t*)&Hs[row * 256 + ((((col >> 3) ^ (row & 7)) << 3) | (col & 7))] = (bf16_t)v;
      }
  __syncthreads();

  // ---- layer 2: out_tile[64][64] = Hs @ W2 (both from LDS, swizzled) ----
  f32x4 acc2[4];
  #pragma unroll
  for (int nf = 0; nf < 4; ++nf) acc2[nf] = (f32x4){0.f, 0.f, 0.f, 0.f};
  const int rowA = wid * 16 + lr;
  #pragma unroll
  for (int ks = 0; ks < 8; ++ks) {
    bf16x8 a = *(const bf16x8*)&Hs[rowA * 256 + (((ks * 4 + lg) ^ (rowA & 7)) << 3)];
    #pragma unroll
    for (int nf = 0; nf < 4; ++nf) {
      int n = nf * 16 + lr;
      bf16x8 b = *(const bf16x8*)&W2s[n * 256 + (((ks * 4 + lg) ^ (n & 7)) << 3)];
      acc2[nf] = __builtin_amdgcn_mfma_f32_16x16x32_bf16(a, b, acc2[nf], 0, 0, 0);
    }
  }

  // ---- epilogue: out = acc2 + b2 (f32) ----
  #pragma unroll
  for (int nf = 0; nf < 4; ++nf) {
    float bb = b2[nf * 16 + lr];
    #pragma unroll
    for (int rr = 0; rr < 4; ++rr) {
      int row = e0 + wid * 16 + lg * 4 + rr;
      out[(size_t)row * 64 + nf * 16 + lr] = acc2[nf][rr] + bb;
    }
  }
}

extern "C" void kernel_launch(void* const* d_in, const int* in_sizes, int n_in,
                              void* d_out, int out_size, void* d_ws, size_t ws_size,
                              hipStream_t stream) {
  const float* src  = (const float*)d_in[0];
  const float* dst  = (const float*)d_in[1];
  const float* ea   = (const float*)d_in[2];
  const float* u    = (const float*)d_in[3];
  const int* batch  = (const int*)d_in[4];
  const float* W1   = (const float*)d_in[5];
  const float* b1   = (const float*)d_in[6];
  const float* W2   = (const float*)d_in[7];
  const float* b2   = (const float*)d_in[8];
  float* out = (float*)d_out;

  u16* W1Ts = (u16*)d_ws;            // 6 chunks x 16384 u16 (chunked+swizzled W1^T)
  u16* W2Ts = W1Ts + 384 * 256;      // "chunk 6": 16384 u16 (swizzled W2^T)

  prep_w1ts<<<(384 * 256 + 255) / 256, 256, 0, stream>>>(W1, W1Ts);
  prep_w2ts<<<(64 * 256 + 255) / 256, 256, 0, stream>>>(W2, W2Ts);
  edge_fused<<<NBLK, 256, 0, stream>>>(src, dst, ea, u, batch, W1Ts, b1, b2, out);
}